// Round 7
// baseline (494.213 us; speedup 1.0000x reference)
//
#include <hip/hip_runtime.h>
#include <cstdint>
#include <cstddef>

#define IN_C 128

typedef _Float16 __attribute__((ext_vector_type(4))) half4v;
typedef _Float16 __attribute__((ext_vector_type(8))) f16x8;
typedef float    __attribute__((ext_vector_type(4))) f32x4;
typedef unsigned __attribute__((ext_vector_type(4))) u32x4;

static __device__ __forceinline__ float lrelu(float x) { return x > 0.f ? x : 0.2f * x; }

static __device__ __forceinline__ float h16_to_f(unsigned short u) {
  union { unsigned short u; _Float16 h; } c; c.u = u;
  return (float)c.h;
}
static __device__ __forceinline__ unsigned pack2h(float a, float b) {
  union { _Float16 h[2]; unsigned u; } c;
  c.h[0] = (_Float16)a; c.h[1] = (_Float16)b;
  return c.u;
}

// ---------------- CSR build ----------------
// count with 8-region partition: r = blockIdx&7 -> atomics stay XCD-local
__global__ void k_count(const int* __restrict__ ei_dst, int* __restrict__ cnt,
                        int E, int Et, int nPerReg, int n) {
  int r = blockIdx.x & 7;
  int e = (blockIdx.x >> 3) * 256 + threadIdx.x;
  if (e >= Et) return;
  int d = (e < E) ? __builtin_nontemporal_load(&ei_dst[e]) : (e - E);
  int lo = r * nPerReg;
  int hi = (r == 7) ? n : lo + nPerReg;
  if (d < lo || d >= hi) return;
  atomicAdd(&cnt[d], 1);
}

__global__ void k_scan1(const int* __restrict__ cnt, int* __restrict__ loc,
                        int* __restrict__ bsum, int n) {
  int tid = threadIdx.x;
  int i = blockIdx.x * 256 + tid;
  int v = (i < n) ? cnt[i] : 0;
  int lane = tid & 63, w = tid >> 6;
  int s = v;
#pragma unroll
  for (int off = 1; off < 64; off <<= 1) {
    int t = __shfl_up(s, off);
    if (lane >= off) s += t;
  }
  __shared__ int wt[4];
  if (lane == 63) wt[w] = s;
  __syncthreads();
  int add = 0;
#pragma unroll
  for (int k = 0; k < 4; ++k)
    if (k < w) add += wt[k];
  int incl = s + add;
  if (i < n) loc[i] = incl - v;
  if (tid == 255) bsum[blockIdx.x] = incl;
}

// merged scan2+scan3: every block redundantly reduces bsum (nb <= 256 values)
__global__ void k_scan3b(const int* __restrict__ loc, const int* __restrict__ bsum,
                         int* __restrict__ row_ptr, int* __restrict__ fill, int n, int nb) {
  int tid = threadIdx.x, b = blockIdx.x;
  int lane = tid & 63, w = tid >> 6;
  int p = 0, t = 0;
  for (int k = tid; k < nb; k += 256) {
    int v = bsum[k];
    t += v;
    if (k < b) p += v;
  }
#pragma unroll
  for (int off = 1; off < 64; off <<= 1) {
    p += __shfl_xor(p, off);
    t += __shfl_xor(t, off);
  }
  __shared__ int sp_[4], st_[4];
  if (lane == 0) { sp_[w] = p; st_[w] = t; }
  __syncthreads();
  p = sp_[0] + sp_[1] + sp_[2] + sp_[3];
  t = st_[0] + st_[1] + st_[2] + st_[3];
  int i = b * 256 + tid;
  if (i < n) {
    int v = loc[i] + p;
    row_ptr[i] = v;
    fill[i] = v;
  }
  if (b == 0 && tid == 0) row_ptr[n] = t;
}

// fused scatter: region-partitioned; layer-1 weights inline;
// writes 16B record {s,d,w4} + compact 4B src stream for layer 2.
__global__ void k_scatter_fused(const int* __restrict__ ei_src, const int* __restrict__ ei_dst,
                                int* __restrict__ fill,
                                const float* __restrict__ as1, const float* __restrict__ ad1,
                                u32x4* __restrict__ recs, int* __restrict__ srcs32,
                                int E, int Et, int nPerReg, int n) {
  int r = blockIdx.x & 7;
  int e = (blockIdx.x >> 3) * 256 + threadIdx.x;
  if (e >= Et) return;
  int d = (e < E) ? __builtin_nontemporal_load(&ei_dst[e]) : (e - E);
  int lo = r * nPerReg;
  int hi = (r == 7) ? n : lo + nPerReg;
  if (d < lo || d >= hi) return;
  int s = (e < E) ? __builtin_nontemporal_load(&ei_src[e]) : d;
  int pos = atomicAdd(&fill[d], 1);
  float4 a = *(const float4*)&as1[s * 4];
  float4 b = *(const float4*)&ad1[d * 4];
  unsigned w01 = pack2h(__expf(lrelu(a.x + b.x)), __expf(lrelu(a.y + b.y)));
  unsigned w23 = pack2h(__expf(lrelu(a.z + b.z)), __expf(lrelu(a.w + b.w)));
  u32x4 rec = {(unsigned)s, (unsigned)d, w01, w23};
  __builtin_nontemporal_store(rec, &recs[pos]);
  __builtin_nontemporal_store(s, &srcs32[pos]);
}

// ---------------- prep: x->fp16 cast + both weight transposes, one launch ----------------
__global__ void k_prep(const float* __restrict__ x, const float* __restrict__ W1,
                       const float* __restrict__ W2, _Float16* __restrict__ xh,
                       _Float16* __restrict__ W1t, _Float16* __restrict__ W2t,
                       int n4, int xb) {
  int b = blockIdx.x;
  if (b < xb) {
    int i = b * 256 + threadIdx.x;
    if (i >= n4) return;
    f32x4 v = __builtin_nontemporal_load((const f32x4*)&x[i * 4]);
    half4v o;
    o.x = (_Float16)v.x; o.y = (_Float16)v.y; o.z = (_Float16)v.z; o.w = (_Float16)v.w;
    *(half4v*)&xh[i * 4] = o;
  } else {
    int i = (b - xb) * 256 + threadIdx.x;
    if (i < 128 * 256) {
      int k = i / 256, nn = i % 256;
      W1t[(size_t)nn * 128 + k] = (_Float16)W1[i];
    } else {
      int j = i - 128 * 256;
      if (j < 256 * 64) {
        int k = j / 64, nn = j % 64;
        W2t[(size_t)nn * 256 + k] = (_Float16)W2[j];
      }
    }
  }
}

// ---------------- MFMA GEMM1 + fused alpha ----------------
__launch_bounds__(256)
__global__ void k_gemm1_a(const _Float16* __restrict__ A, const _Float16* __restrict__ Bt,
                          const float* __restrict__ a_s, const float* __restrict__ a_d,
                          _Float16* __restrict__ C, float* __restrict__ as1,
                          float* __restrict__ ad1, int M) {
  int w = threadIdx.x >> 6, lane = threadIdx.x & 63;
  int r = lane & 15, kg = lane >> 4;
  int m0 = blockIdx.x * 64 + w * 16;
  f32x4 acc[16];
#pragma unroll
  for (int c = 0; c < 16; ++c) acc[c] = (f32x4){0.f, 0.f, 0.f, 0.f};
  int mA = m0 + r; if (mA > M - 1) mA = M - 1;
  const _Float16* Arow = A + (size_t)mA * 128 + kg * 8;
#pragma unroll
  for (int k0 = 0; k0 < 128; k0 += 32) {
    f16x8 a = __builtin_nontemporal_load((const f16x8*)(Arow + k0));
#pragma unroll
    for (int c = 0; c < 16; ++c) {
      f16x8 b = *(const f16x8*)&Bt[(size_t)(c * 16 + r) * 128 + k0 + kg * 8];
      acc[c] = __builtin_amdgcn_mfma_f32_16x16x32_f16(a, b, acc[c], 0, 0, 0);
    }
  }
  float sp[4][4] = {}, dp[4][4] = {};
#pragma unroll
  for (int c = 0; c < 16; ++c) {
    float asv = a_s[c * 16 + r];
    float adv = a_d[c * 16 + r];
#pragma unroll
    for (int j = 0; j < 4; ++j) {
      float v = acc[c][j];
      sp[c >> 2][j] += v * asv;
      dp[c >> 2][j] += v * adv;
    }
  }
#pragma unroll
  for (int off = 1; off < 16; off <<= 1) {
#pragma unroll
    for (int h = 0; h < 4; ++h)
#pragma unroll
      for (int j = 0; j < 4; ++j) {
        sp[h][j] += __shfl_xor(sp[h][j], off);
        dp[h][j] += __shfl_xor(dp[h][j], off);
      }
  }
#pragma unroll
  for (int c = 0; c < 16; ++c) {
#pragma unroll
    for (int j = 0; j < 4; ++j) {
      int m = m0 + kg * 4 + j;
      if (m < M) C[(size_t)m * 256 + c * 16 + r] = (_Float16)acc[c][j];
    }
  }
  if (r == 0) {
#pragma unroll
    for (int j = 0; j < 4; ++j) {
      int m = m0 + kg * 4 + j;
      if (m < M) {
#pragma unroll
        for (int h = 0; h < 4; ++h) {
          as1[m * 4 + h] = sp[h][j];
          ad1[m * 4 + h] = dp[h][j];
        }
      }
    }
  }
}

// ---------------- MFMA GEMM2 + fused alpha ----------------
__launch_bounds__(256)
__global__ void k_gemm2_a(const _Float16* __restrict__ A, const _Float16* __restrict__ Bt,
                          const float* __restrict__ a_s, const float* __restrict__ a_d,
                          _Float16* __restrict__ C, float* __restrict__ as2,
                          float* __restrict__ ad2, int M) {
  int w = threadIdx.x >> 6, lane = threadIdx.x & 63;
  int r = lane & 15, kg = lane >> 4;
  int m0 = blockIdx.x * 64 + w * 16;
  f32x4 acc[4];
#pragma unroll
  for (int c = 0; c < 4; ++c) acc[c] = (f32x4){0.f, 0.f, 0.f, 0.f};
  int mA = m0 + r; if (mA > M - 1) mA = M - 1;
  const _Float16* Arow = A + (size_t)mA * 256 + kg * 8;
#pragma unroll
  for (int k0 = 0; k0 < 256; k0 += 32) {
    f16x8 a = __builtin_nontemporal_load((const f16x8*)(Arow + k0));
#pragma unroll
    for (int c = 0; c < 4; ++c) {
      f16x8 b = *(const f16x8*)&Bt[(size_t)(c * 16 + r) * 256 + k0 + kg * 8];
      acc[c] = __builtin_amdgcn_mfma_f32_16x16x32_f16(a, b, acc[c], 0, 0, 0);
    }
  }
  float sp[4] = {}, dp[4] = {};
#pragma unroll
  for (int c = 0; c < 4; ++c) {
    float asv = a_s[c * 16 + r];
    float adv = a_d[c * 16 + r];
#pragma unroll
    for (int j = 0; j < 4; ++j) {
      float v = acc[c][j];
      sp[j] += v * asv;
      dp[j] += v * adv;
    }
  }
#pragma unroll
  for (int off = 1; off < 16; off <<= 1) {
#pragma unroll
    for (int j = 0; j < 4; ++j) {
      sp[j] += __shfl_xor(sp[j], off);
      dp[j] += __shfl_xor(dp[j], off);
    }
  }
#pragma unroll
  for (int c = 0; c < 4; ++c) {
#pragma unroll
    for (int j = 0; j < 4; ++j) {
      int m = m0 + kg * 4 + j;
      if (m < M) C[(size_t)m * 64 + c * 16 + r] = (_Float16)acc[c][j];
    }
  }
  if (r == 0) {
#pragma unroll
    for (int j = 0; j < 4; ++j) {
      int m = m0 + kg * 4 + j;
      if (m < M) { as2[m] = sp[j]; ad2[m] = dp[j]; }
    }
  }
}

// ---------------- aggregation, layer 1: 4 edges in flight, NT rec stream ----------------
__launch_bounds__(256)
__global__ void k_aggr1(const int* __restrict__ row_ptr, const u32x4* __restrict__ recs,
                        const _Float16* __restrict__ h1h, const float* __restrict__ b1,
                        _Float16* __restrict__ hrelu_h, int n) {
  int wave = threadIdx.x >> 6, lane = threadIdx.x & 63;
  int node = blockIdx.x * 4 + wave;
  if (node >= n) return;
  int beg = row_ptr[node], end = row_ptr[node + 1];
  int g = lane >> 4, l16 = lane & 15;
  int ch0 = l16 * 16;      // 16 lanes x 16 ch = 256
  int myh = l16 >> 2;      // 4 lanes per head
  float acc[16] = {};
  float dsum = 0.f;
  for (int i = beg; i < end; i += 4) {
    int idx = i + g;
    int s = 0; float w = 0.f;
    if (idx < end) {
      u32x4 rc = __builtin_nontemporal_load(&recs[idx]);
      s = (int)rc.x;
      unsigned wp = (myh & 2) ? rc.w : rc.z;
      w = h16_to_f((myh & 1) ? (unsigned short)(wp >> 16) : (unsigned short)(wp & 0xffffu));
    }
    const _Float16* hp = &h1h[(size_t)s * 256 + ch0];
    f16x8 hA = *(const f16x8*)hp;
    f16x8 hB = *(const f16x8*)(hp + 8);
    dsum += w;
#pragma unroll
    for (int j = 0; j < 8; ++j) acc[j] += w * (float)hA[j];
#pragma unroll
    for (int j = 0; j < 8; ++j) acc[8 + j] += w * (float)hB[j];
  }
#pragma unroll
  for (int off = 16; off < 64; off <<= 1) {
    dsum += __shfl_xor(dsum, off);
#pragma unroll
    for (int j = 0; j < 16; ++j) acc[j] += __shfl_xor(acc[j], off);
  }
  if (g == 0) {
    float inv = 1.0f / (dsum + 1e-16f);
    f16x8 oA, oB;
#pragma unroll
    for (int j = 0; j < 8; ++j) {
      oA[j] = (_Float16)fmaxf(acc[j] * inv + b1[ch0 + j], 0.f);
      oB[j] = (_Float16)fmaxf(acc[8 + j] * inv + b1[ch0 + 8 + j], 0.f);
    }
    _Float16* op = &hrelu_h[(size_t)node * 256 + ch0];
    __builtin_nontemporal_store(oA, (f16x8*)op);
    __builtin_nontemporal_store(oB, (f16x8*)(op + 8));
  }
}

// ---------------- aggregation, layer 2: compact src stream, fused weights ----------------
__launch_bounds__(256)
__global__ void k_aggr2(const int* __restrict__ row_ptr, const int* __restrict__ srcs32,
                        const float* __restrict__ as2, const float* __restrict__ ad2,
                        const _Float16* __restrict__ h2h, const float* __restrict__ b2,
                        float* __restrict__ out, int n) {
  int wave = threadIdx.x >> 6, lane = threadIdx.x & 63;
  int node = blockIdx.x * 4 + wave;
  if (node >= n) return;
  int beg = row_ptr[node], end = row_ptr[node + 1];
  float adm = ad2[node];
  int g = lane >> 4, l16 = lane & 15;
  int ch0 = l16 * 4;       // 16 lanes x 4 ch = 64
  float acc[4] = {};
  float dsum = 0.f;
  for (int i = beg; i < end; i += 4) {
    int idx = i + g;
    int s = 0; float w = 0.f;
    if (idx < end) {
      s = __builtin_nontemporal_load(&srcs32[idx]);
      w = __expf(lrelu(as2[s] + adm));
    }
    half4v hv = *(const half4v*)&h2h[(size_t)s * 64 + ch0];
    dsum += w;
    acc[0] += w * (float)hv.x; acc[1] += w * (float)hv.y;
    acc[2] += w * (float)hv.z; acc[3] += w * (float)hv.w;
  }
#pragma unroll
  for (int off = 16; off < 64; off <<= 1) {
    dsum += __shfl_xor(dsum, off);
#pragma unroll
    for (int j = 0; j < 4; ++j) acc[j] += __shfl_xor(acc[j], off);
  }
  if (g == 0) {
    float inv = 1.0f / (dsum + 1e-16f);
    f32x4 o;
    o.x = acc[0] * inv + b2[ch0];
    o.y = acc[1] * inv + b2[ch0 + 1];
    o.z = acc[2] * inv + b2[ch0 + 2];
    o.w = acc[3] * inv + b2[ch0 + 3];
    __builtin_nontemporal_store(o, (f32x4*)&out[(size_t)node * 64 + ch0]);
  }
}

// ---------------- launch ----------------
extern "C" void kernel_launch(void* const* d_in, const int* in_sizes, int n_in,
                              void* d_out, int out_size, void* d_ws, size_t ws_size,
                              hipStream_t stream) {
  const float* x    = (const float*)d_in[0];
  const int*   ei   = (const int*)d_in[1];
  const float* W1   = (const float*)d_in[2];
  const float* a_s1 = (const float*)d_in[3];
  const float* a_d1 = (const float*)d_in[4];
  const float* b1   = (const float*)d_in[5];
  const float* W2   = (const float*)d_in[6];
  const float* a_s2 = (const float*)d_in[7];
  const float* a_d2 = (const float*)d_in[8];
  const float* b2   = (const float*)d_in[9];
  float* out = (float*)d_out;

  const int n  = in_sizes[0] / IN_C;  // 50000
  const int E  = in_sizes[1] / 2;     // 1600000
  const int Et = E + n;
  const int* ei_src = ei;
  const int* ei_dst = ei + E;

  char* ws = (char*)d_ws;
  size_t off = 0;
  auto alloc = [&](size_t bytes) -> void* {
    void* p = ws + off;
    off = (off + bytes + 255) & ~(size_t)255;
    return p;
  };
  _Float16* xh      = (_Float16*)alloc((size_t)n * 128 * 2);
  _Float16* W1t     = (_Float16*)alloc((size_t)256 * 128 * 2);
  _Float16* W2t     = (_Float16*)alloc((size_t)64 * 256 * 2);
  _Float16* h1h     = (_Float16*)alloc((size_t)n * 256 * 2);
  _Float16* hrelu_h = (_Float16*)alloc((size_t)n * 256 * 2);
  _Float16* h2h     = (_Float16*)alloc((size_t)n * 64 * 2);
  float* as1        = (float*)alloc((size_t)n * 4 * 4);
  float* ad1        = (float*)alloc((size_t)n * 4 * 4);
  float* as2        = (float*)alloc((size_t)n * 4);
  float* ad2        = (float*)alloc((size_t)n * 4);
  int* cnt          = (int*)alloc((size_t)n * 4);
  int* loc          = (int*)alloc((size_t)n * 4);
  int* row_ptr      = (int*)alloc((size_t)(n + 1) * 4);
  int* fill         = (int*)alloc((size_t)n * 4);
  int* bsum         = (int*)alloc((size_t)256 * 4);
  u32x4* recs       = (u32x4*)alloc((size_t)Et * 16);
  int* srcs32       = (int*)alloc((size_t)Et * 4);

  int eb  = (Et + 255) / 256;
  int nb  = (n + 255) / 256;
  int nw  = (n + 3) / 4;
  int gx1 = (n + 63) / 64;
  int nPerReg = (n + 7) / 8;
  int n4  = n * 128 / 4;
  int xb  = (n4 + 255) / 256;
  int wb  = (128 * 256 + 256 * 64 + 255) / 256;

  // CSR count + scan
  (void)hipMemsetAsync(cnt, 0, (size_t)n * 4, stream);
  hipLaunchKernelGGL(k_count, dim3(eb * 8), dim3(256), 0, stream, ei_dst, cnt, E, Et, nPerReg, n);
  hipLaunchKernelGGL(k_scan1, dim3(nb), dim3(256), 0, stream, cnt, loc, bsum, n);
  hipLaunchKernelGGL(k_scan3b, dim3(nb), dim3(256), 0, stream, loc, bsum, row_ptr, fill, n, nb);

  // prep (x cast + W transposes)
  hipLaunchKernelGGL(k_prep, dim3(xb + wb), dim3(256), 0, stream, x, W1, W2, xh, W1t, W2t, n4, xb);

  // layer 1
  hipLaunchKernelGGL(k_gemm1_a, dim3(gx1), dim3(256), 0, stream,
                     xh, W1t, a_s1, a_d1, h1h, as1, ad1, n);
  hipLaunchKernelGGL(k_scatter_fused, dim3(eb * 8), dim3(256), 0, stream,
                     ei_src, ei_dst, fill, as1, ad1, recs, srcs32, E, Et, nPerReg, n);
  hipLaunchKernelGGL(k_aggr1, dim3(nw), dim3(256), 0, stream, row_ptr, recs, h1h, b1, hrelu_h, n);

  // layer 2
  hipLaunchKernelGGL(k_gemm2_a, dim3(gx1), dim3(256), 0, stream,
                     hrelu_h, W2t, a_s2, a_d2, h2h, as2, ad2, n);
  hipLaunchKernelGGL(k_aggr2, dim3(nw), dim3(256), 0, stream,
                     row_ptr, srcs32, as2, ad2, h2h, b2, out, n);
}